// Round 4
// baseline (493.069 us; speedup 1.0000x reference)
//
#include <hip/hip_runtime.h>
#include <hip/hip_bf16.h>
#include <stdint.h>

#define T_LEN   16384
#define HID     1024
#define KDIM    1024
#define CHUNK   64
#define NCHUNK  256   // T_LEN / CHUNK

typedef __bf16 bf16x8  __attribute__((ext_vector_type(8)));
typedef float  f32x16  __attribute__((ext_vector_type(16)));

__device__ inline ushort f2bf(float f) {
  union { float f; uint32_t u; } v; v.f = f;
  uint32_t r = v.u + 0x7FFF + ((v.u >> 16) & 1);   // RNE
  return (ushort)(r >> 16);
}
__device__ inline float bf2f(ushort u) {
  union { uint32_t u; float f; } v; v.u = ((uint32_t)u) << 16;
  return v.f;
}

__device__ inline void gload16(const void* g, void* l) {
  __builtin_amdgcn_global_load_lds(
      (const __attribute__((address_space(1))) void*)g,
      (__attribute__((address_space(3))) void*)l, 16, 0, 0);
}

// ---------------- prep: lambda (complex), exp(gamma) ----------------
__global__ __launch_bounds__(256) void prep_kernel(
    const float* __restrict__ nu_log, const float* __restrict__ theta_log,
    const float* __restrict__ gamma_log,
    float* __restrict__ lam_re, float* __restrict__ lam_im, float* __restrict__ eg) {
  int h = blockIdx.x * 256 + threadIdx.x;
  if (h < HID) {
    float mag = expf(-expf(nu_log[h]));
    float th  = expf(theta_log[h]);
    lam_re[h] = mag * cosf(th);
    lam_im[h] = mag * sinf(th);
    eg[h]     = expf(gamma_log[h]);
  }
}

// ---------------- fp32 -> bf16, vectorized x4 ----------------
__global__ __launch_bounds__(256) void convX(
    const float* __restrict__ src, ushort* __restrict__ dst) {
  size_t i = ((size_t)blockIdx.x * 256 + threadIdx.x) * 4;
  float4 v = *(const float4*)(src + i);
  ushort4 o;
  o.x = f2bf(v.x); o.y = f2bf(v.y); o.z = f2bf(v.z); o.w = f2bf(v.w);
  *(ushort4*)(dst + i) = o;
}

// ---------------- all weight prep in one kernel (z selects job) ----------------
__global__ __launch_bounds__(256) void weight_prep(
    const float* __restrict__ Bre, const float* __restrict__ Bim,
    const float* __restrict__ Cre, const float* __restrict__ Cim,
    const float* __restrict__ D,   const float* __restrict__ eg,
    ushort* __restrict__ BreT, ushort* __restrict__ BimT,
    ushort* __restrict__ CreB, ushort* __restrict__ CimB,
    ushort* __restrict__ DT) {
  __shared__ float tile[32][33];
  int z = blockIdx.z;
  if (z == 2 || z == 3) {                       // straight convert (C matrices)
    const float* src = (z == 2) ? Cre : Cim;
    ushort* dst = (z == 2) ? CreB : CimB;
    float s = (z == 2) ? 1.0f : -1.0f;
    size_t base = ((size_t)blockIdx.y * 32 + (threadIdx.x >> 3)) * 1024 +
                  blockIdx.x * 32 + (threadIdx.x & 7) * 4;
    float4 v = *(const float4*)(src + base);
    ushort4 o;
    o.x = f2bf(v.x * s); o.y = f2bf(v.y * s);
    o.z = f2bf(v.z * s); o.w = f2bf(v.w * s);
    *(ushort4*)(dst + base) = o;
    return;
  }
  const float* src = (z == 0) ? Bre : (z == 1) ? Bim : D;
  ushort* dst = (z == 0) ? BreT : (z == 1) ? BimT : DT;
  bool scaled = (z < 2);
  int bx = blockIdx.x * 32;   // n-block
  int by = blockIdx.y * 32;   // k-block
  int tx = threadIdx.x & 31, ty = threadIdx.x >> 5;   // 32 x 8
#pragma unroll
  for (int r = 0; r < 32; r += 8)
    tile[ty + r][tx] = src[(size_t)(by + ty + r) * 1024 + bx + tx];
  __syncthreads();
  float sc = scaled ? eg[by + tx] : 1.0f;
#pragma unroll
  for (int r = 0; r < 32; r += 8)
    dst[(size_t)(bx + ty + r) * 1024 + by + tx] = f2bf(tile[tx][ty + r] * sc);
}

// ---------------- MFMA GEMM core: 32x32x16, 128x128 tile, 4 waves 2x2 ----------
// A: M x K bf16 (K contig). B: N x K bf16 (K contig). BK=32.
// Wave sub-tile 64x64 = 2x2 tiles of 32x32. A/B operand: row=lane&31,
// k=(lane>>5)*8+j. C/D: col=lane&31, row=(reg&3)+8*(reg>>2)+4*(lane>>5).
__device__ __forceinline__ void gemm_accum32(
    const ushort* __restrict__ A, const ushort* __restrict__ B,
    ushort* As, ushort* Bs, int tb, int nb, f32x16 acc[2][2]) {
  const int tid = threadIdx.x;
  const int w = tid >> 6, l = tid & 63;
  const int wrow = w & 1, wcol = w >> 1;
  const int lr = l & 31;          // row within 32-tile
  const int kh = (l >> 5) * 8;    // k offset within 16-slice
  const int rs = l >> 2;          // staging row within 16-row window
  const int cs = (l & 3) * 8;     // staging k offset (ushorts)
  for (int k0 = 0; k0 < KDIM; k0 += 32) {
#pragma unroll
    for (int i = 0; i < 2; ++i) {
      int win = w * 2 + i;
      int r = win * 16 + rs;
      gload16(A + (size_t)(tb + r) * KDIM + k0 + cs, As + win * 512);
      gload16(B + (size_t)(nb + r) * KDIM + k0 + cs, Bs + win * 512);
    }
    __syncthreads();
    bf16x8 af[2][2], bf[2][2];
#pragma unroll
    for (int it = 0; it < 2; ++it)
#pragma unroll
      for (int ks = 0; ks < 2; ++ks) {
        af[it][ks] = *(const bf16x8*)(As + (wrow * 64 + it * 32 + lr) * 32 + ks * 16 + kh);
        bf[it][ks] = *(const bf16x8*)(Bs + (wcol * 64 + it * 32 + lr) * 32 + ks * 16 + kh);
      }
#pragma unroll
    for (int it = 0; it < 2; ++it)
#pragma unroll
      for (int jt = 0; jt < 2; ++jt)
#pragma unroll
        for (int ks = 0; ks < 2; ++ks)
          acc[it][jt] = __builtin_amdgcn_mfma_f32_32x32x16_bf16(
              af[it][ks], bf[jt][ks], acc[it][jt], 0, 0, 0);
    __syncthreads();
  }
}

// ---------------- dual-B GEMM: BuRe/BuIm bf16 in one pass ----------------
__global__ __launch_bounds__(256) void gemm_bu(
    const ushort* __restrict__ A, const ushort* __restrict__ B1,
    const ushort* __restrict__ B2,
    ushort* __restrict__ O1, ushort* __restrict__ O2) {
  __shared__ __align__(16) ushort As[4096], Bs1[4096], Bs2[4096];
  f32x16 acc1[2][2], acc2[2][2];
#pragma unroll
  for (int i = 0; i < 2; ++i)
#pragma unroll
    for (int j = 0; j < 2; ++j) {
      acc1[i][j] = (f32x16)(0.f);
      acc2[i][j] = (f32x16)(0.f);
    }
  const int tid = threadIdx.x;
  const int w = tid >> 6, l = tid & 63;
  const int wrow = w & 1, wcol = w >> 1;
  const int lr = l & 31;
  const int kh = (l >> 5) * 8;
  const int rs = l >> 2;
  const int cs = (l & 3) * 8;
  const int tb = blockIdx.x * 128, nb = blockIdx.y * 128;
  for (int k0 = 0; k0 < KDIM; k0 += 32) {
#pragma unroll
    for (int i = 0; i < 2; ++i) {
      int win = w * 2 + i;
      int r = win * 16 + rs;
      gload16(A  + (size_t)(tb + r) * KDIM + k0 + cs, As  + win * 512);
      gload16(B1 + (size_t)(nb + r) * KDIM + k0 + cs, Bs1 + win * 512);
      gload16(B2 + (size_t)(nb + r) * KDIM + k0 + cs, Bs2 + win * 512);
    }
    __syncthreads();
    bf16x8 af[2][2], b1[2][2], b2[2][2];
#pragma unroll
    for (int it = 0; it < 2; ++it)
#pragma unroll
      for (int ks = 0; ks < 2; ++ks) {
        af[it][ks] = *(const bf16x8*)(As  + (wrow * 64 + it * 32 + lr) * 32 + ks * 16 + kh);
        b1[it][ks] = *(const bf16x8*)(Bs1 + (wcol * 64 + it * 32 + lr) * 32 + ks * 16 + kh);
        b2[it][ks] = *(const bf16x8*)(Bs2 + (wcol * 64 + it * 32 + lr) * 32 + ks * 16 + kh);
      }
#pragma unroll
    for (int it = 0; it < 2; ++it)
#pragma unroll
      for (int jt = 0; jt < 2; ++jt)
#pragma unroll
        for (int ks = 0; ks < 2; ++ks) {
          acc1[it][jt] = __builtin_amdgcn_mfma_f32_32x32x16_bf16(
              af[it][ks], b1[jt][ks], acc1[it][jt], 0, 0, 0);
          acc2[it][jt] = __builtin_amdgcn_mfma_f32_32x32x16_bf16(
              af[it][ks], b2[jt][ks], acc2[it][jt], 0, 0, 0);
        }
    __syncthreads();
  }
  const int rb = 4 * (l >> 5);
#pragma unroll
  for (int it = 0; it < 2; ++it)
#pragma unroll
    for (int jt = 0; jt < 2; ++jt) {
      int col = nb + wcol * 64 + jt * 32 + lr;
#pragma unroll
      for (int reg = 0; reg < 16; ++reg) {
        int row = tb + wrow * 64 + it * 32 + (reg & 3) + 8 * (reg >> 2) + rb;
        O1[(size_t)row * HID + col] = f2bf(acc1[it][jt][reg]);
        O2[(size_t)row * HID + col] = f2bf(acc2[it][jt][reg]);
      }
    }
}

// ---------------- out = Hre@Cre^T + Him@(-Cim)^T + X@D^T ----------------
__global__ __launch_bounds__(256) void gemm3(
    const ushort* __restrict__ A1, const ushort* __restrict__ B1,
    const ushort* __restrict__ A2, const ushort* __restrict__ B2,
    const ushort* __restrict__ A3, const ushort* __restrict__ B3,
    float* __restrict__ O) {
  __shared__ __align__(16) ushort As[4096], Bs[4096];
  f32x16 acc[2][2];
#pragma unroll
  for (int i = 0; i < 2; ++i)
#pragma unroll
    for (int j = 0; j < 2; ++j) acc[i][j] = (f32x16)(0.f);
  int tb = blockIdx.x * 128, nb = blockIdx.y * 128;
  gemm_accum32(A1, B1, As, Bs, tb, nb, acc);
  gemm_accum32(A2, B2, As, Bs, tb, nb, acc);
  gemm_accum32(A3, B3, As, Bs, tb, nb, acc);
  const int tid = threadIdx.x;
  const int w = tid >> 6, l = tid & 63;
  const int wrow = w & 1, wcol = w >> 1;
  const int lr = l & 31;
  const int rb = 4 * (l >> 5);
#pragma unroll
  for (int it = 0; it < 2; ++it)
#pragma unroll
    for (int jt = 0; jt < 2; ++jt) {
      int col = nb + wcol * 64 + jt * 32 + lr;
#pragma unroll
      for (int reg = 0; reg < 16; ++reg) {
        int row = tb + wrow * 64 + it * 32 + (reg & 3) + 8 * (reg >> 2) + rb;
        O[(size_t)row * HID + col] = acc[it][jt][reg];
      }
    }
}

// ---------------- scan pass A: chunk sums only ----------------
__global__ __launch_bounds__(256) void scan_sums(
    const ushort* __restrict__ BuRe, const ushort* __restrict__ BuIm,
    const float* __restrict__ lam_re, const float* __restrict__ lam_im,
    float* __restrict__ Sre, float* __restrict__ Sim) {
  int h0 = (blockIdx.y * 256 + threadIdx.x) * 2;
  int c = blockIdx.x;
  float lr0 = lam_re[h0], li0 = lam_im[h0];
  float lr1 = lam_re[h0 + 1], li1 = lam_im[h0 + 1];
  float hr0 = 0.f, hi0 = 0.f, hr1 = 0.f, hi1 = 0.f;
  size_t base = ((size_t)c * CHUNK * HID + h0) >> 1;   // uint index
  const uint* Re = (const uint*)BuRe;
  const uint* Im = (const uint*)BuIm;
#pragma unroll 4
  for (int t = 0; t < CHUNK; ++t) {
    uint re = Re[base + (size_t)t * (HID / 2)];
    uint im = Im[base + (size_t)t * (HID / 2)];
    float br0 = bf2f((ushort)re), br1 = bf2f((ushort)(re >> 16));
    float bi0 = bf2f((ushort)im), bi1 = bf2f((ushort)(im >> 16));
    float nr0 = fmaf(lr0, hr0, fmaf(-li0, hi0, br0));
    float ni0 = fmaf(lr0, hi0, fmaf(li0, hr0, bi0));
    float nr1 = fmaf(lr1, hr1, fmaf(-li1, hi1, br1));
    float ni1 = fmaf(lr1, hi1, fmaf(li1, hr1, bi1));
    hr0 = nr0; hi0 = ni0; hr1 = nr1; hi1 = ni1;
  }
  Sre[(size_t)c * HID + h0] = hr0;  Sre[(size_t)c * HID + h0 + 1] = hr1;
  Sim[(size_t)c * HID + h0] = hi0;  Sim[(size_t)c * HID + h0 + 1] = hi1;
}

// ---------------- scan pass 2: serial carry scan over chunks ----------------
__global__ __launch_bounds__(256) void scan_carry(
    const float* __restrict__ Sre, const float* __restrict__ Sim,
    const float* __restrict__ lam_re, const float* __restrict__ lam_im,
    float* __restrict__ Pre, float* __restrict__ Pim) {
  int h = blockIdx.x * 256 + threadIdx.x;
  float lr = lam_re[h], li = lam_im[h];
  float pr = lr, pi = li;       // lambda^64 via 6 squarings
#pragma unroll
  for (int s = 0; s < 6; ++s) {
    float nr = pr * pr - pi * pi;
    float ni = 2.f * pr * pi;
    pr = nr; pi = ni;
  }
  float cr = 0.f, ci = 0.f;
  for (int c = 0; c < NCHUNK; ++c) {
    Pre[(size_t)c * HID + h] = cr;
    Pim[(size_t)c * HID + h] = ci;
    float sr = Sre[(size_t)c * HID + h];
    float si = Sim[(size_t)c * HID + h];
    float nr = fmaf(pr, cr, fmaf(-pi, ci, sr));
    float ni = fmaf(pr, ci, fmaf(pi, cr, si));
    cr = nr; ci = ni;
  }
}

// ---------------- scan pass B: replay with carry init, emit bf16 H -------------
__global__ __launch_bounds__(256) void scan_emit(
    const ushort* __restrict__ BuRe, const ushort* __restrict__ BuIm,
    const float* __restrict__ lam_re, const float* __restrict__ lam_im,
    const float* __restrict__ Pre, const float* __restrict__ Pim,
    ushort* __restrict__ HbfRe, ushort* __restrict__ HbfIm) {
  int h0 = (blockIdx.y * 256 + threadIdx.x) * 2;
  int c = blockIdx.x;
  float lr0 = lam_re[h0], li0 = lam_im[h0];
  float lr1 = lam_re[h0 + 1], li1 = lam_im[h0 + 1];
  float hr0 = Pre[(size_t)c * HID + h0], hi0 = Pim[(size_t)c * HID + h0];
  float hr1 = Pre[(size_t)c * HID + h0 + 1], hi1 = Pim[(size_t)c * HID + h0 + 1];
  size_t base = ((size_t)c * CHUNK * HID + h0) >> 1;
  const uint* Re = (const uint*)BuRe;
  const uint* Im = (const uint*)BuIm;
  uint* ORe = (uint*)HbfRe;
  uint* OIm = (uint*)HbfIm;
#pragma unroll 4
  for (int t = 0; t < CHUNK; ++t) {
    uint re = Re[base + (size_t)t * (HID / 2)];
    uint im = Im[base + (size_t)t * (HID / 2)];
    float br0 = bf2f((ushort)re), br1 = bf2f((ushort)(re >> 16));
    float bi0 = bf2f((ushort)im), bi1 = bf2f((ushort)(im >> 16));
    float nr0 = fmaf(lr0, hr0, fmaf(-li0, hi0, br0));
    float ni0 = fmaf(lr0, hi0, fmaf(li0, hr0, bi0));
    float nr1 = fmaf(lr1, hr1, fmaf(-li1, hi1, br1));
    float ni1 = fmaf(lr1, hi1, fmaf(li1, hr1, bi1));
    hr0 = nr0; hi0 = ni0; hr1 = nr1; hi1 = ni1;
    ORe[base + (size_t)t * (HID / 2)] = (uint)f2bf(hr0) | ((uint)f2bf(hr1) << 16);
    OIm[base + (size_t)t * (HID / 2)] = (uint)f2bf(hi0) | ((uint)f2bf(hi1) << 16);
  }
}

extern "C" void kernel_launch(void* const* d_in, const int* in_sizes, int n_in,
                              void* d_out, int out_size, void* d_ws, size_t ws_size,
                              hipStream_t stream) {
  const float* inputs    = (const float*)d_in[0];
  const float* nu_log    = (const float*)d_in[1];
  const float* theta_log = (const float*)d_in[2];
  const float* gamma_log = (const float*)d_in[3];
  const float* B_re      = (const float*)d_in[4];
  const float* B_im      = (const float*)d_in[5];
  const float* C_re      = (const float*)d_in[6];
  const float* C_im      = (const float*)d_in[7];
  const float* D         = (const float*)d_in[8];
  float* out = (float*)d_out;

  char* ws = (char*)d_ws;
  constexpr size_t TH = (size_t)T_LEN * HID;
  constexpr size_t W  = (size_t)1024 * 1024;
  constexpr size_t CH = (size_t)NCHUNK * HID;

  ushort* Xbf   = (ushort*)(ws);
  ushort* BuRe  = (ushort*)(ws + TH * 2);
  ushort* BuIm  = (ushort*)(ws + TH * 4);
  ushort* HbfRe = (ushort*)(ws + TH * 6);
  ushort* HbfIm = (ushort*)(ws + TH * 8);
  char*   p     = ws + TH * 10;
  ushort* BreT  = (ushort*)(p);            p += W * 2;
  ushort* BimT  = (ushort*)(p);            p += W * 2;
  ushort* CreB  = (ushort*)(p);            p += W * 2;
  ushort* CimB  = (ushort*)(p);            p += W * 2;
  ushort* DT    = (ushort*)(p);            p += W * 2;
  float*  Sre   = (float*)(p);             p += CH * 4;
  float*  Sim   = (float*)(p);             p += CH * 4;
  float*  Pre   = (float*)(p);             p += CH * 4;
  float*  Pim   = (float*)(p);             p += CH * 4;
  float*  lamR  = (float*)(p);             p += 4096;
  float*  lamI  = (float*)(p);             p += 4096;
  float*  eg    = (float*)(p);             p += 4096;

  prep_kernel<<<dim3(HID / 256), 256, 0, stream>>>(nu_log, theta_log, gamma_log,
                                                   lamR, lamI, eg);
  convX<<<dim3((unsigned)(TH / 4 / 256)), 256, 0, stream>>>(inputs, Xbf);
  weight_prep<<<dim3(32, 32, 5), 256, 0, stream>>>(B_re, B_im, C_re, C_im, D, eg,
                                                   BreT, BimT, CreB, CimB, DT);

  gemm_bu<<<dim3(T_LEN / 128, HID / 128), 256, 0, stream>>>(Xbf, BreT, BimT,
                                                            BuRe, BuIm);

  scan_sums<<<dim3(NCHUNK, HID / 512), 256, 0, stream>>>(BuRe, BuIm, lamR, lamI,
                                                         Sre, Sim);
  scan_carry<<<dim3(HID / 256), 256, 0, stream>>>(Sre, Sim, lamR, lamI, Pre, Pim);
  scan_emit<<<dim3(NCHUNK, HID / 512), 256, 0, stream>>>(BuRe, BuIm, lamR, lamI,
                                                         Pre, Pim, HbfRe, HbfIm);

  gemm3<<<dim3(T_LEN / 128, HID / 128), 256, 0, stream>>>(HbfRe, CreB, HbfIm, CimB,
                                                          Xbf, DT, out);
}

// Round 5
// 411.088 us; speedup vs baseline: 1.1994x; 1.1994x over previous
//
#include <hip/hip_runtime.h>
#include <hip/hip_bf16.h>
#include <stdint.h>

#define T_LEN   16384
#define HID     1024
#define KDIM    1024
#define CHUNK   64
#define NCHUNK  256   // T_LEN / CHUNK

typedef __bf16 bf16x8 __attribute__((ext_vector_type(8)));
typedef float  f32x4  __attribute__((ext_vector_type(4)));

__device__ inline ushort f2bf(float f) {
  union { float f; uint32_t u; } v; v.f = f;
  uint32_t r = v.u + 0x7FFF + ((v.u >> 16) & 1);   // RNE
  return (ushort)(r >> 16);
}
__device__ inline float bf2f(ushort u) {
  union { uint32_t u; float f; } v; v.u = ((uint32_t)u) << 16;
  return v.f;
}

__device__ inline void gload16(const void* g, void* l) {
  __builtin_amdgcn_global_load_lds(
      (const __attribute__((address_space(1))) void*)g,
      (__attribute__((address_space(3))) void*)l, 16, 0, 0);
}

// ---------------- prep: lambda (complex), exp(gamma) ----------------
__global__ __launch_bounds__(256) void prep_kernel(
    const float* __restrict__ nu_log, const float* __restrict__ theta_log,
    const float* __restrict__ gamma_log,
    float* __restrict__ lam_re, float* __restrict__ lam_im, float* __restrict__ eg) {
  int h = blockIdx.x * 256 + threadIdx.x;
  if (h < HID) {
    float mag = expf(-expf(nu_log[h]));
    float th  = expf(theta_log[h]);
    lam_re[h] = mag * cosf(th);
    lam_im[h] = mag * sinf(th);
    eg[h]     = expf(gamma_log[h]);
  }
}

// ---------------- fp32 -> bf16, vectorized x4 ----------------
__global__ __launch_bounds__(256) void convX(
    const float* __restrict__ src, ushort* __restrict__ dst) {
  size_t i = ((size_t)blockIdx.x * 256 + threadIdx.x) * 4;
  float4 v = *(const float4*)(src + i);
  ushort4 o;
  o.x = f2bf(v.x); o.y = f2bf(v.y); o.z = f2bf(v.z); o.w = f2bf(v.w);
  *(ushort4*)(dst + i) = o;
}

// ---------------- all weight prep in one kernel (z selects job) ----------------
// z=0: BreT[n*1024+k]=B_re[k*1024+n]*eg[k]  z=1: same B_im
// z=2: CreB=bf16(C_re)  z=3: CimB=bf16(-C_im)  z=4: DT[n*1024+k]=D[k*1024+n]
__global__ __launch_bounds__(256) void weight_prep(
    const float* __restrict__ Bre, const float* __restrict__ Bim,
    const float* __restrict__ Cre, const float* __restrict__ Cim,
    const float* __restrict__ D,   const float* __restrict__ eg,
    ushort* __restrict__ BreT, ushort* __restrict__ BimT,
    ushort* __restrict__ CreB, ushort* __restrict__ CimB,
    ushort* __restrict__ DT) {
  __shared__ float tile[32][33];
  int z = blockIdx.z;
  if (z == 2 || z == 3) {
    const float* src = (z == 2) ? Cre : Cim;
    ushort* dst = (z == 2) ? CreB : CimB;
    float s = (z == 2) ? 1.0f : -1.0f;
    size_t base = ((size_t)blockIdx.y * 32 + (threadIdx.x >> 3)) * 1024 +
                  blockIdx.x * 32 + (threadIdx.x & 7) * 4;
    float4 v = *(const float4*)(src + base);
    ushort4 o;
    o.x = f2bf(v.x * s); o.y = f2bf(v.y * s);
    o.z = f2bf(v.z * s); o.w = f2bf(v.w * s);
    *(ushort4*)(dst + base) = o;
    return;
  }
  const float* src = (z == 0) ? Bre : (z == 1) ? Bim : D;
  ushort* dst = (z == 0) ? BreT : (z == 1) ? BimT : DT;
  bool scaled = (z < 2);
  int bx = blockIdx.x * 32;   // n-block
  int by = blockIdx.y * 32;   // k-block
  int tx = threadIdx.x & 31, ty = threadIdx.x >> 5;
#pragma unroll
  for (int r = 0; r < 32; r += 8)
    tile[ty + r][tx] = src[(size_t)(by + ty + r) * 1024 + bx + tx];
  __syncthreads();
  float sc = scaled ? eg[by + tx] : 1.0f;
#pragma unroll
  for (int r = 0; r < 32; r += 8)
    dst[(size_t)(bx + ty + r) * 1024 + by + tx] = f2bf(tile[tx][ty + r] * sc);
}

// ---------------- MFMA GEMM core (m97 structure, 16x16x32) ----------------
// A: M x K bf16, row stride lda. B: N x K bf16, row stride 1024. BK=32.
__device__ __forceinline__ void gemm_accum(
    const ushort* __restrict__ A, int lda, const ushort* __restrict__ B,
    ushort* As, ushort* Bs, int tb, int nb, f32x4 acc[4][4]) {
  const int tid = threadIdx.x;
  const int w = tid >> 6, l = tid & 63;
  const int wrow = w & 1, wcol = w >> 1;
  const int lo = l & 15, q = l >> 4;
  const int rs = l >> 2;
  const int cs = (l & 3) * 8;
  for (int k0 = 0; k0 < KDIM; k0 += 32) {
#pragma unroll
    for (int i = 0; i < 2; ++i) {
      int win = w * 2 + i;
      int r = win * 16 + rs;
      gload16(A + (size_t)(tb + r) * lda + k0 + cs, As + win * 512);
      gload16(B + (size_t)(nb + r) * KDIM + k0 + cs, Bs + win * 512);
    }
    __syncthreads();
    bf16x8 af[4], bfr[4];
#pragma unroll
    for (int i = 0; i < 4; ++i) {
      af[i]  = *(const bf16x8*)(As + (wrow * 64 + i * 16 + lo) * 32 + q * 8);
      bfr[i] = *(const bf16x8*)(Bs + (wcol * 64 + i * 16 + lo) * 32 + q * 8);
    }
#pragma unroll
    for (int i = 0; i < 4; ++i)
#pragma unroll
      for (int j = 0; j < 4; ++j)
        acc[i][j] = __builtin_amdgcn_mfma_f32_16x16x32_bf16(af[i], bfr[j], acc[i][j], 0, 0, 0);
    __syncthreads();
  }
}

// ---------------- Bu GEMM: X @ [BreT;BimT]^T -> bf16 T x 2048 ----------------
__global__ __launch_bounds__(256) void gemm_bu(
    const ushort* __restrict__ A, const ushort* __restrict__ B,
    ushort* __restrict__ O) {
  __shared__ __align__(16) ushort As[4096], Bs[4096];
  f32x4 acc[4][4];
#pragma unroll
  for (int i = 0; i < 4; ++i)
#pragma unroll
    for (int j = 0; j < 4; ++j) acc[i][j] = (f32x4){0.f, 0.f, 0.f, 0.f};
  int tb = blockIdx.x * 128, nb = blockIdx.y * 128;
  gemm_accum(A, KDIM, B, As, Bs, tb, nb, acc);
  const int tid = threadIdx.x;
  const int w = tid >> 6, l = tid & 63;
  const int wrow = w & 1, wcol = w >> 1;
  const int lo = l & 15, q = l >> 4;
#pragma unroll
  for (int i = 0; i < 4; ++i)
#pragma unroll
    for (int j = 0; j < 4; ++j) {
      int col = nb + wcol * 64 + j * 16 + lo;
#pragma unroll
      for (int r = 0; r < 4; ++r) {
        int row = tb + wrow * 64 + i * 16 + q * 4 + r;
        O[(size_t)row * 2048 + col] = f2bf(acc[i][j][r]);
      }
    }
}

// ---------------- out = Hre@Cre^T + Him@(-Cim)^T + X@D^T ----------------
// Hall: T x 2048 (Re at col 0, Im at col 1024)
__global__ __launch_bounds__(256) void gemm3(
    const ushort* __restrict__ Hall,
    const ushort* __restrict__ CreB, const ushort* __restrict__ CimB,
    const ushort* __restrict__ X,    const ushort* __restrict__ DT,
    float* __restrict__ O) {
  __shared__ __align__(16) ushort As[4096], Bs[4096];
  f32x4 acc[4][4];
#pragma unroll
  for (int i = 0; i < 4; ++i)
#pragma unroll
    for (int j = 0; j < 4; ++j) acc[i][j] = (f32x4){0.f, 0.f, 0.f, 0.f};
  int tb = blockIdx.x * 128, nb = blockIdx.y * 128;
  gemm_accum(Hall,        2048, CreB, As, Bs, tb, nb, acc);
  gemm_accum(Hall + 1024, 2048, CimB, As, Bs, tb, nb, acc);
  gemm_accum(X,           1024, DT,   As, Bs, tb, nb, acc);
  const int tid = threadIdx.x;
  const int w = tid >> 6, l = tid & 63;
  const int wrow = w & 1, wcol = w >> 1;
  const int lo = l & 15, q = l >> 4;
#pragma unroll
  for (int i = 0; i < 4; ++i)
#pragma unroll
    for (int j = 0; j < 4; ++j) {
      int col = nb + wcol * 64 + j * 16 + lo;
#pragma unroll
      for (int r = 0; r < 4; ++r) {
        int row = tb + wrow * 64 + i * 16 + q * 4 + r;
        O[(size_t)row * HID + col] = acc[i][j][r];
      }
    }
}

// ---------------- scan pass A: chunk sums only (Bu: T x 2048 bf16) -------------
__global__ __launch_bounds__(256) void scan_sums(
    const ushort* __restrict__ Bu,
    const float* __restrict__ lam_re, const float* __restrict__ lam_im,
    float* __restrict__ Sre, float* __restrict__ Sim) {
  int h0 = (blockIdx.y * 256 + threadIdx.x) * 2;
  int c = blockIdx.x;
  float lr0 = lam_re[h0], li0 = lam_im[h0];
  float lr1 = lam_re[h0 + 1], li1 = lam_im[h0 + 1];
  float hr0 = 0.f, hi0 = 0.f, hr1 = 0.f, hi1 = 0.f;
  const uint* P = (const uint*)Bu;
  size_t baseR = (size_t)c * CHUNK * 1024 + (h0 >> 1);          // uint idx, row stride 1024
  size_t baseI = baseR + 512;
#pragma unroll 8
  for (int t = 0; t < CHUNK; ++t) {
    uint re = P[baseR + (size_t)t * 1024];
    uint im = P[baseI + (size_t)t * 1024];
    float br0 = bf2f((ushort)re), br1 = bf2f((ushort)(re >> 16));
    float bi0 = bf2f((ushort)im), bi1 = bf2f((ushort)(im >> 16));
    float nr0 = fmaf(lr0, hr0, fmaf(-li0, hi0, br0));
    float ni0 = fmaf(lr0, hi0, fmaf(li0, hr0, bi0));
    float nr1 = fmaf(lr1, hr1, fmaf(-li1, hi1, br1));
    float ni1 = fmaf(lr1, hi1, fmaf(li1, hr1, bi1));
    hr0 = nr0; hi0 = ni0; hr1 = nr1; hi1 = ni1;
  }
  Sre[(size_t)c * HID + h0] = hr0;  Sre[(size_t)c * HID + h0 + 1] = hr1;
  Sim[(size_t)c * HID + h0] = hi0;  Sim[(size_t)c * HID + h0 + 1] = hi1;
}

// ---------------- scan pass 2: serial carry scan over chunks ----------------
__global__ __launch_bounds__(256) void scan_carry(
    const float* __restrict__ Sre, const float* __restrict__ Sim,
    const float* __restrict__ lam_re, const float* __restrict__ lam_im,
    float* __restrict__ Pre, float* __restrict__ Pim) {
  int h = blockIdx.x * 256 + threadIdx.x;
  float lr = lam_re[h], li = lam_im[h];
  float pr = lr, pi = li;       // lambda^64 via 6 squarings
#pragma unroll
  for (int s = 0; s < 6; ++s) {
    float nr = pr * pr - pi * pi;
    float ni = 2.f * pr * pi;
    pr = nr; pi = ni;
  }
  float cr = 0.f, ci = 0.f;
  for (int c = 0; c < NCHUNK; ++c) {
    Pre[(size_t)c * HID + h] = cr;
    Pim[(size_t)c * HID + h] = ci;
    float sr = Sre[(size_t)c * HID + h];
    float si = Sim[(size_t)c * HID + h];
    float nr = fmaf(pr, cr, fmaf(-pi, ci, sr));
    float ni = fmaf(pr, ci, fmaf(pi, cr, si));
    cr = nr; ci = ni;
  }
}

// ---------------- scan pass B: replay with carry init, emit bf16 Hall ----------
__global__ __launch_bounds__(256) void scan_emit(
    const ushort* __restrict__ Bu,
    const float* __restrict__ lam_re, const float* __restrict__ lam_im,
    const float* __restrict__ Pre, const float* __restrict__ Pim,
    ushort* __restrict__ Hall) {
  int h0 = (blockIdx.y * 256 + threadIdx.x) * 2;
  int c = blockIdx.x;
  float lr0 = lam_re[h0], li0 = lam_im[h0];
  float lr1 = lam_re[h0 + 1], li1 = lam_im[h0 + 1];
  float hr0 = Pre[(size_t)c * HID + h0], hi0 = Pim[(size_t)c * HID + h0];
  float hr1 = Pre[(size_t)c * HID + h0 + 1], hi1 = Pim[(size_t)c * HID + h0 + 1];
  const uint* P = (const uint*)Bu;
  uint* Q = (uint*)Hall;
  size_t baseR = (size_t)c * CHUNK * 1024 + (h0 >> 1);
  size_t baseI = baseR + 512;
#pragma unroll 8
  for (int t = 0; t < CHUNK; ++t) {
    uint re = P[baseR + (size_t)t * 1024];
    uint im = P[baseI + (size_t)t * 1024];
    float br0 = bf2f((ushort)re), br1 = bf2f((ushort)(re >> 16));
    float bi0 = bf2f((ushort)im), bi1 = bf2f((ushort)(im >> 16));
    float nr0 = fmaf(lr0, hr0, fmaf(-li0, hi0, br0));
    float ni0 = fmaf(lr0, hi0, fmaf(li0, hr0, bi0));
    float nr1 = fmaf(lr1, hr1, fmaf(-li1, hi1, br1));
    float ni1 = fmaf(lr1, hi1, fmaf(li1, hr1, bi1));
    hr0 = nr0; hi0 = ni0; hr1 = nr1; hi1 = ni1;
    Q[baseR + (size_t)t * 1024] = (uint)f2bf(hr0) | ((uint)f2bf(hr1) << 16);
    Q[baseI + (size_t)t * 1024] = (uint)f2bf(hi0) | ((uint)f2bf(hi1) << 16);
  }
}

extern "C" void kernel_launch(void* const* d_in, const int* in_sizes, int n_in,
                              void* d_out, int out_size, void* d_ws, size_t ws_size,
                              hipStream_t stream) {
  const float* inputs    = (const float*)d_in[0];
  const float* nu_log    = (const float*)d_in[1];
  const float* theta_log = (const float*)d_in[2];
  const float* gamma_log = (const float*)d_in[3];
  const float* B_re      = (const float*)d_in[4];
  const float* B_im      = (const float*)d_in[5];
  const float* C_re      = (const float*)d_in[6];
  const float* C_im      = (const float*)d_in[7];
  const float* D         = (const float*)d_in[8];
  float* out = (float*)d_out;

  char* ws = (char*)d_ws;
  constexpr size_t TH = (size_t)T_LEN * HID;       // 16.8M
  constexpr size_t W  = (size_t)1024 * 1024;
  constexpr size_t CH = (size_t)NCHUNK * HID;

  ushort* Xbf  = (ushort*)(ws);                    // TH*2
  ushort* Bu   = (ushort*)(ws + TH * 2);           // TH*2*2 (T x 2048)
  ushort* Hall = (ushort*)(ws + TH * 6);           // TH*2*2 (T x 2048)
  char*   p    = ws + TH * 10;
  ushort* Ball = (ushort*)(p);             p += 2 * W * 2;   // [BreT; BimT]
  ushort* CreB = (ushort*)(p);             p += W * 2;
  ushort* CimB = (ushort*)(p);             p += W * 2;
  ushort* DT   = (ushort*)(p);             p += W * 2;
  float*  Sre  = (float*)(p);              p += CH * 4;
  float*  Sim  = (float*)(p);              p += CH * 4;
  float*  Pre  = (float*)(p);              p += CH * 4;
  float*  Pim  = (float*)(p);              p += CH * 4;
  float*  lamR = (float*)(p);              p += 4096;
  float*  lamI = (float*)(p);              p += 4096;
  float*  eg   = (float*)(p);              p += 4096;
  ushort* BreT = Ball;
  ushort* BimT = Ball + W;

  prep_kernel<<<dim3(HID / 256), 256, 0, stream>>>(nu_log, theta_log, gamma_log,
                                                   lamR, lamI, eg);
  convX<<<dim3((unsigned)(TH / 4 / 256)), 256, 0, stream>>>(inputs, Xbf);
  weight_prep<<<dim3(32, 32, 5), 256, 0, stream>>>(B_re, B_im, C_re, C_im, D, eg,
                                                   BreT, BimT, CreB, CimB, DT);

  gemm_bu<<<dim3(T_LEN / 128, 2048 / 128), 256, 0, stream>>>(Xbf, Ball, Bu);

  scan_sums<<<dim3(NCHUNK, HID / 512), 256, 0, stream>>>(Bu, lamR, lamI, Sre, Sim);
  scan_carry<<<dim3(HID / 256), 256, 0, stream>>>(Sre, Sim, lamR, lamI, Pre, Pim);
  scan_emit<<<dim3(NCHUNK, HID / 512), 256, 0, stream>>>(Bu, lamR, lamI, Pre, Pim,
                                                         Hall);

  gemm3<<<dim3(T_LEN / 128, HID / 128), 256, 0, stream>>>(Hall, CreB, CimB, Xbf, DT,
                                                          out);
}